// Round 1
// baseline (42.833 us; speedup 1.0000x reference)
//
#include <hip/hip_runtime.h>

// NeRF fused render: B rays x S samples, MLP 3->64(relu)->4(exp), alpha composite.
// Decomposition: 8 lanes per ray, 16 contiguous samples per lane.
// First MLP layer folded to per-ray affine: pre_h(m) = A_h + m*B_h.

constexpr int S_TOTAL = 128;
constexpr int TPR     = 8;             // threads (lanes) per ray
constexpr int SPT     = S_TOTAL / TPR; // 16 samples per thread
constexpr int BLOCK   = 256;
constexpr int H       = 64;

__global__ __launch_bounds__(BLOCK, 4)
void nerf_fused(const float* __restrict__ origins,
                const float* __restrict__ directions,
                const float* __restrict__ nearp,
                const float* __restrict__ farp,
                const float* __restrict__ W1,   // [3][64]
                const float* __restrict__ b1,   // [64]
                const float* __restrict__ W2,   // [64][4]
                const float* __restrict__ b2,   // [4]
                float* __restrict__ out,        // [B][3]
                int B)
{
    // packed per-hidden-unit weights: {W1[0][h],W1[1][h],W1[2][h],b1[h], W2[h][0..3]}
    __shared__ float pk[H][8];
    __shared__ float b2s[4];

    const int tid = threadIdx.x;
    if (tid < H) {
        pk[tid][0] = W1[0 * H + tid];
        pk[tid][1] = W1[1 * H + tid];
        pk[tid][2] = W1[2 * H + tid];
        pk[tid][3] = b1[tid];
        pk[tid][4] = W2[tid * 4 + 0];
        pk[tid][5] = W2[tid * 4 + 1];
        pk[tid][6] = W2[tid * 4 + 2];
        pk[tid][7] = W2[tid * 4 + 3];
    }
    if (tid < 4) b2s[tid] = b2[tid];
    __syncthreads();

    const int gtid = blockIdx.x * BLOCK + tid;
    const int ray  = gtid >> 3;          // / TPR
    const int sub  = gtid & (TPR - 1);   // lane within ray group
    if (ray >= B) return;

    const float o0 = origins[ray * 3 + 0];
    const float o1 = origins[ray * 3 + 1];
    const float o2 = origins[ray * 3 + 2];
    float d0 = directions[ray * 3 + 0];
    float d1 = directions[ray * 3 + 1];
    float d2 = directions[ray * 3 + 2];

    const float nr    = nearp[0];
    const float fr    = farp[0];
    const float delta = (fr - nr) * (1.0f / (float)S_TOTAL);

    const float nrm  = sqrtf(d0 * d0 + d1 * d1 + d2 * d2);
    const float rinv = 1.0f / fmaxf(nrm, 1e-12f);
    d0 *= rinv; d1 *= rinv; d2 *= rinv;

    // sample midpoints for this lane's chunk: m_s = near + (s + 0.5)*delta
    float m[SPT];
#pragma unroll
    for (int k = 0; k < SPT; ++k)
        m[k] = fmaf((float)(sub * SPT + k) + 0.5f, delta, nr);

    const float b20 = b2s[0], b21 = b2s[1], b22 = b2s[2], b23 = b2s[3];
    float4 acc[SPT];
#pragma unroll
    for (int k = 0; k < SPT; ++k) acc[k] = make_float4(b20, b21, b22, b23);

#pragma unroll 4
    for (int h = 0; h < H; ++h) {
        const float4 pa = *reinterpret_cast<const float4*>(&pk[h][0]); // w1x,w1y,w1z,b1
        const float4 pb = *reinterpret_cast<const float4*>(&pk[h][4]); // w2[0..3]
        const float Ah = fmaf(o2, pa.z, fmaf(o1, pa.y, fmaf(o0, pa.x, pa.w)));
        const float Bh = fmaf(d2, pa.z, fmaf(d1, pa.y, d0 * pa.x));
#pragma unroll
        for (int k = 0; k < SPT; ++k) {
            const float hv = fmaxf(fmaf(m[k], Bh, Ah), 0.0f);
            acc[k].x = fmaf(hv, pb.x, acc[k].x);
            acc[k].y = fmaf(hv, pb.y, acc[k].y);
            acc[k].z = fmaf(hv, pb.z, acc[k].z);
            acc[k].w = fmaf(hv, pb.w, acc[k].w);
        }
    }

    // local (in-order) composite over this lane's 16 samples
    float Tloc = 1.0f, orr = 0.0f, og = 0.0f, ob = 0.0f;
#pragma unroll
    for (int k = 0; k < SPT; ++k) {
        const float sig = __expf(acc[k].w);
        const float e   = __expf(-sig * delta);  // = 1 - alpha
        Tloc *= e;                               // inclusive cumprod
        const float w = Tloc * (1.0f - e);       // T * alpha
        orr = fmaf(w, __expf(acc[k].x), orr);
        og  = fmaf(w, __expf(acc[k].y), og);
        ob  = fmaf(w, __expf(acc[k].z), ob);
    }

    // stitch across the 8 lanes of this ray:
    // inclusive scan-product of Tloc, then exclusive prefix for scaling
    float scan = Tloc;
#pragma unroll
    for (int off = 1; off < TPR; off <<= 1) {
        const float v = __shfl_up(scan, off, TPR);
        if (sub >= off) scan *= v;
    }
    float pre = __shfl_up(scan, 1, TPR);
    if (sub == 0) pre = 1.0f;

    orr *= pre; og *= pre; ob *= pre;
#pragma unroll
    for (int off = TPR / 2; off > 0; off >>= 1) {
        orr += __shfl_down(orr, off, TPR);
        og  += __shfl_down(og,  off, TPR);
        ob  += __shfl_down(ob,  off, TPR);
    }

    if (sub == 0) {
        out[ray * 3 + 0] = orr;
        out[ray * 3 + 1] = og;
        out[ray * 3 + 2] = ob;
    }
}

extern "C" void kernel_launch(void* const* d_in, const int* in_sizes, int n_in,
                              void* d_out, int out_size, void* d_ws, size_t ws_size,
                              hipStream_t stream) {
    const float* origins    = (const float*)d_in[0];
    const float* directions = (const float*)d_in[1];
    const float* nearp      = (const float*)d_in[2];
    const float* farp       = (const float*)d_in[3];
    const float* W1         = (const float*)d_in[4];
    const float* b1         = (const float*)d_in[5];
    const float* W2         = (const float*)d_in[6];
    const float* b2         = (const float*)d_in[7];
    float* out              = (float*)d_out;

    const int B     = in_sizes[0] / 3;       // 32768
    const int total = B * TPR;
    const int grid  = (total + BLOCK - 1) / BLOCK;

    nerf_fused<<<grid, BLOCK, 0, stream>>>(origins, directions, nearp, farp,
                                           W1, b1, W2, b2, out, B);
}

// Round 2
// 40.688 us; speedup vs baseline: 1.0527x; 1.0527x over previous
//
#include <hip/hip_runtime.h>

// NeRF fused render: B rays x S samples, MLP 3->64(relu)->4(exp), alpha composite.
// R2: 16 lanes per ray (8 samples/lane) for 32 waves/CU occupancy; per-(ray,h)
// affine fold A_h + m*B_h precomputed cooperatively into LDS.

constexpr int S_TOTAL = 128;
constexpr int TPR     = 16;            // threads (lanes) per ray
constexpr int SPT     = S_TOTAL / TPR; // 8 samples per thread
constexpr int BLOCK   = 256;
constexpr int RPB     = BLOCK / TPR;   // 16 rays per block
constexpr int H       = 64;

__global__ __launch_bounds__(BLOCK, 8)
void nerf_fused(const float* __restrict__ origins,
                const float* __restrict__ directions,
                const float* __restrict__ nearp,
                const float* __restrict__ farp,
                const float* __restrict__ W1,   // [3][64]
                const float* __restrict__ b1,   // [64]
                const float* __restrict__ W2,   // [64][4]
                const float* __restrict__ b2,   // [4]
                float* __restrict__ out,        // [B][3]
                int B)
{
    // per-(ray,h) affine fold: ABs[r][h] = {A,B} with pre_h(m) = A + m*B
    // pad h-dim by 1 => ray stride 520B => 4 per-wave addrs land in distinct banks
    __shared__ float ABs[RPB][H + 1][2];
    __shared__ float W2s[H][4];
    __shared__ float b2s[4];

    const int tid  = threadIdx.x;
    const int ray0 = blockIdx.x * RPB;

    if (tid < H) {
        W2s[tid][0] = W2[tid * 4 + 0];
        W2s[tid][1] = W2[tid * 4 + 1];
        W2s[tid][2] = W2[tid * 4 + 2];
        W2s[tid][3] = W2[tid * 4 + 3];
    }
    if (tid < 4) b2s[tid] = b2[tid];

#pragma unroll
    for (int idx = tid; idx < RPB * H; idx += BLOCK) {
        const int r   = idx >> 6;        // / H
        const int h   = idx & (H - 1);
        const int ray = ray0 + r;
        const float o0 = origins[ray * 3 + 0];
        const float o1 = origins[ray * 3 + 1];
        const float o2 = origins[ray * 3 + 2];
        float d0 = directions[ray * 3 + 0];
        float d1 = directions[ray * 3 + 1];
        float d2 = directions[ray * 3 + 2];
        const float nrm  = sqrtf(d0 * d0 + d1 * d1 + d2 * d2);
        const float rinv = 1.0f / fmaxf(nrm, 1e-12f);
        d0 *= rinv; d1 *= rinv; d2 *= rinv;
        const float w0 = W1[0 * H + h];
        const float w1 = W1[1 * H + h];
        const float w2 = W1[2 * H + h];
        ABs[r][h][0] = fmaf(o2, w2, fmaf(o1, w1, fmaf(o0, w0, b1[h])));
        ABs[r][h][1] = fmaf(d2, w2, fmaf(d1, w1, d0 * w0));
    }
    __syncthreads();

    const int sub  = tid & (TPR - 1);    // lane within ray group
    const int rloc = tid >> 4;           // local ray index (log2(TPR)=4)
    const int ray  = ray0 + rloc;

    const float nr    = nearp[0];
    const float fr    = farp[0];
    const float delta = (fr - nr) * (1.0f / (float)S_TOTAL);

    // sample midpoints for this lane's chunk: m_s = near + (s + 0.5)*delta
    float m[SPT];
#pragma unroll
    for (int k = 0; k < SPT; ++k)
        m[k] = fmaf((float)(sub * SPT + k) + 0.5f, delta, nr);

    const float b20 = b2s[0], b21 = b2s[1], b22 = b2s[2], b23 = b2s[3];
    float4 acc[SPT];
#pragma unroll
    for (int k = 0; k < SPT; ++k) acc[k] = make_float4(b20, b21, b22, b23);

#pragma unroll 4
    for (int h = 0; h < H; ++h) {
        const float2 ab = *reinterpret_cast<const float2*>(&ABs[rloc][h][0]);
        const float4 pb = *reinterpret_cast<const float4*>(&W2s[h][0]);
#pragma unroll
        for (int k = 0; k < SPT; ++k) {
            const float hv = fmaxf(fmaf(m[k], ab.y, ab.x), 0.0f);
            acc[k].x = fmaf(hv, pb.x, acc[k].x);
            acc[k].y = fmaf(hv, pb.y, acc[k].y);
            acc[k].z = fmaf(hv, pb.z, acc[k].z);
            acc[k].w = fmaf(hv, pb.w, acc[k].w);
        }
    }

    // local (in-order) composite over this lane's 8 samples
    float Tloc = 1.0f, orr = 0.0f, og = 0.0f, ob = 0.0f;
#pragma unroll
    for (int k = 0; k < SPT; ++k) {
        const float sig = __expf(acc[k].w);
        const float e   = __expf(-sig * delta);  // = 1 - alpha
        Tloc *= e;                               // inclusive cumprod
        const float w = Tloc * (1.0f - e);       // T * alpha
        orr = fmaf(w, __expf(acc[k].x), orr);
        og  = fmaf(w, __expf(acc[k].y), og);
        ob  = fmaf(w, __expf(acc[k].z), ob);
    }

    // stitch across the 16 lanes of this ray:
    // inclusive scan-product of Tloc, then exclusive prefix for scaling
    float scan = Tloc;
#pragma unroll
    for (int off = 1; off < TPR; off <<= 1) {
        const float v = __shfl_up(scan, off, TPR);
        if (sub >= off) scan *= v;
    }
    float pre = __shfl_up(scan, 1, TPR);
    if (sub == 0) pre = 1.0f;

    orr *= pre; og *= pre; ob *= pre;
#pragma unroll
    for (int off = TPR / 2; off > 0; off >>= 1) {
        orr += __shfl_down(orr, off, TPR);
        og  += __shfl_down(og,  off, TPR);
        ob  += __shfl_down(ob,  off, TPR);
    }

    if (sub == 0) {
        out[ray * 3 + 0] = orr;
        out[ray * 3 + 1] = og;
        out[ray * 3 + 2] = ob;
    }
}

extern "C" void kernel_launch(void* const* d_in, const int* in_sizes, int n_in,
                              void* d_out, int out_size, void* d_ws, size_t ws_size,
                              hipStream_t stream) {
    const float* origins    = (const float*)d_in[0];
    const float* directions = (const float*)d_in[1];
    const float* nearp      = (const float*)d_in[2];
    const float* farp       = (const float*)d_in[3];
    const float* W1         = (const float*)d_in[4];
    const float* b1         = (const float*)d_in[5];
    const float* W2         = (const float*)d_in[6];
    const float* b2         = (const float*)d_in[7];
    float* out              = (float*)d_out;

    const int B     = in_sizes[0] / 3;       // 32768
    const int total = B * TPR;
    const int grid  = (total + BLOCK - 1) / BLOCK;

    nerf_fused<<<grid, BLOCK, 0, stream>>>(origins, directions, nearp, farp,
                                           W1, b1, W2, b2, out, B);
}